// Round 4
// baseline (482.880 us; speedup 1.0000x reference)
//
#include <hip/hip_runtime.h>

// SNN classifier: T=500, B=256, 96 -> 64 -> 80, leaky (subtract reset).
// f32 BLAS-order arithmetic replicated exactly (single-accumulator
// k-ascending __fmaf_rn chains; leaky update op-sequence fixed) -> outputs
// bitwise-identical to the passing round-2/3 kernels.
//
// Round-4: round-3's K1 was 76us: VGPR=56 proved the W1 column spilled
// (W1 re-loaded per FMA) and LDS float4 broadcasts oversubscribed the LDS
// pipe ~6x (4 scalars per ~12cyc ds_read_b128, 4 waves per LDS unit).
// Fix: give every FMA a per-lane VGPR operand + a wave-UNIFORM operand
// fetched on the scalar/VMEM-broadcast path. No LDS in K1 at all.
//
//   K1: 1-wave blocks, lane=h. W1 column in regs (launch_bounds(64,3)
//       -> 170 VGPR budget, ~116 needed). x rows are blockIdx-uniform
//       float4 loads. Coalesced 256B stores. grid 256*25.
//   K2: unchanged (chunk-prefetched in-place recurrence).
//   K3: 1-wave blocks, lane=t (64-t tile). spk row per lane in 64 VGPRs,
//       W2 rows uniform float4 loads, acc[40] x 2 o-halves, h ascending.
//       Output transposed via 64x41 LDS tile (bank-conflict-free) ->
//       coalesced stores into cur2[t][b][o] so K4 stays in-place-safe.
//   K4: unchanged.

#define T_STEPS 500
#define BATCH   256
#define N_IN    96
#define N_HID   64
#define N_OUT   80
#define CH      50   // chunk size in K2/K4 (500 = 10*50)

// ---------------- K1: cur1 = x @ W1 + b1 ----------------
// grid 256*25, block 64. Each block: one b, 20 timesteps.
__global__ __launch_bounds__(64, 3) void k1_cur1(
    const float* __restrict__ x,   // (T,B,96)
    const float* __restrict__ W1,  // (96,64)
    const float* __restrict__ b1,  // (64)
    float* __restrict__ cur1)      // (T,B,64) region inside outs
{
    const int b  = blockIdx.x / 25;
    const int tc = blockIdx.x % 25;
    const int h  = threadIdx.x;    // 0..63

    float w[N_IN];
    #pragma unroll
    for (int k = 0; k < N_IN; ++k) w[k] = W1[k * N_HID + h];
    const float bb = b1[h];

    const int t0 = tc * 20;
    #pragma unroll 2
    for (int tl = 0; tl < 20; ++tl) {
        const int t = t0 + tl;
        const float4* __restrict__ xr =
            reinterpret_cast<const float4*>(x + ((size_t)t * BATCH + b) * N_IN);
        float acc = 0.0f;
        #pragma unroll
        for (int k4 = 0; k4 < N_IN / 4; ++k4) {
            const float4 xv = xr[k4];          // wave-uniform load
            acc = __fmaf_rn(xv.x, w[k4 * 4 + 0], acc);
            acc = __fmaf_rn(xv.y, w[k4 * 4 + 1], acc);
            acc = __fmaf_rn(xv.z, w[k4 * 4 + 2], acc);
            acc = __fmaf_rn(xv.w, w[k4 * 4 + 3], acc);
        }
        cur1[((size_t)t * BATCH + b) * N_HID + h] = __fadd_rn(acc, bb);
    }
}

// ---------------- K2: layer-1 recurrence (in-place cur1 -> spk) ----------------
__global__ __launch_bounds__(64) void k2_rec1(float* cs)  // outs region
{
    const int b = blockIdx.x;
    const int h = threadIdx.x;
    const size_t str  = (size_t)BATCH * N_HID;
    const size_t base = (size_t)b * N_HID + h;

    float A[CH], Bv[CH];
    #pragma unroll
    for (int i = 0; i < CH; ++i) A[i] = cs[(size_t)i * str + base];

    float mem = 0.f, s = 0.f;
    for (int cp = 0; cp < 5; ++cp) {            // 10 chunks, processed in pairs
        const int c0 = 2 * cp;
        #pragma unroll
        for (int i = 0; i < CH; ++i)            // prefetch chunk c0+1
            Bv[i] = cs[(size_t)((c0 + 1) * CH + i) * str + base];
        #pragma unroll
        for (int i = 0; i < CH; ++i) {          // compute chunk c0 from A
            const float m = __fsub_rn(__fadd_rn(__fmul_rn(0.95f, mem), A[i]), s);
            mem = m; s = (m > 1.0f) ? 1.0f : 0.0f;
            cs[(size_t)(c0 * CH + i) * str + base] = s;
        }
        if (cp < 4) {
            #pragma unroll
            for (int i = 0; i < CH; ++i)        // prefetch chunk c0+2
                A[i] = cs[(size_t)((c0 + 2) * CH + i) * str + base];
        }
        #pragma unroll
        for (int i = 0; i < CH; ++i) {          // compute chunk c0+1 from Bv
            const float m = __fsub_rn(__fadd_rn(__fmul_rn(0.95f, mem), Bv[i]), s);
            mem = m; s = (m > 1.0f) ? 1.0f : 0.0f;
            cs[(size_t)((c0 + 1) * CH + i) * str + base] = s;
        }
    }
}

// ---------------- K3: cur2 = spk @ W2 + b2 ----------------
// grid 256*8, block 64. Each block: one b, one 64-t tile (last tile 52).
__global__ __launch_bounds__(64, 3) void k3_cur2(
    const float* __restrict__ spk,  // (T,B,64) in outs
    const float* __restrict__ W2,   // (64,80)
    const float* __restrict__ b2,   // (80)
    float* __restrict__ cur2)       // (T,B,80) = outm region
{
    const int b    = blockIdx.x >> 3;
    const int tc   = blockIdx.x & 7;
    const int lane = threadIdx.x;           // = t within tile
    const int t    = tc * 64 + lane;        // 0..511
    const int tt   = (t < T_STEPS) ? t : (T_STEPS - 1);  // clamp loads

    // per-lane spk row (64 floats) -> VGPRs
    float sr[N_HID];
    {
        const float4* __restrict__ sp =
            reinterpret_cast<const float4*>(spk + ((size_t)tt * BATCH + b) * N_HID);
        #pragma unroll
        for (int k4 = 0; k4 < N_HID / 4; ++k4) {
            const float4 v = sp[k4];
            sr[k4 * 4 + 0] = v.x; sr[k4 * 4 + 1] = v.y;
            sr[k4 * 4 + 2] = v.z; sr[k4 * 4 + 3] = v.w;
        }
    }

    __shared__ float cs[64][41];            // pad 41 -> bank stride 9, conflict-free

    #pragma unroll 1
    for (int half = 0; half < 2; ++half) {
        const int o0 = half * 40;
        float acc[40];
        #pragma unroll
        for (int o = 0; o < 40; ++o) acc[o] = 0.0f;

        #pragma unroll
        for (int h = 0; h < N_HID; ++h) {   // ascending-h single-acc chains
            const float4* __restrict__ wr =
                reinterpret_cast<const float4*>(W2 + (size_t)h * N_OUT + o0);
            const float sv = sr[h];
            #pragma unroll
            for (int o4 = 0; o4 < 10; ++o4) {
                const float4 wv = wr[o4];   // wave-uniform load
                acc[o4 * 4 + 0] = __fmaf_rn(sv, wv.x, acc[o4 * 4 + 0]);
                acc[o4 * 4 + 1] = __fmaf_rn(sv, wv.y, acc[o4 * 4 + 1]);
                acc[o4 * 4 + 2] = __fmaf_rn(sv, wv.z, acc[o4 * 4 + 2]);
                acc[o4 * 4 + 3] = __fmaf_rn(sv, wv.w, acc[o4 * 4 + 3]);
            }
        }

        // add bias, park in LDS transposed
        #pragma unroll
        for (int o = 0; o < 40; ++o)
            cs[lane][o] = __fadd_rn(acc[o], b2[o0 + o]);   // uniform b2 load

        // single wave per block: LDS ordering within the wave is tracked by
        // lgkmcnt; no barrier needed.
        for (int tr = 0; tr < 64; ++tr) {
            const int tg = tc * 64 + tr;
            if (lane < 40 && tg < T_STEPS)
                cur2[((size_t)tg * BATCH + b) * N_OUT + o0 + lane] = cs[tr][lane];
        }
    }
}

// ---------------- K4: layer-2 recurrence (cur2 in outm -> spk/mem finals) ----------------
__global__ __launch_bounds__(80) void k4_rec2(float* cm, float* os)
{
    const int b = blockIdx.x;
    const int o = threadIdx.x;   // 0..79
    const size_t str  = (size_t)BATCH * N_OUT;
    const size_t base = (size_t)b * N_OUT + o;

    float A[CH], Bv[CH];
    #pragma unroll
    for (int i = 0; i < CH; ++i) A[i] = cm[(size_t)i * str + base];

    float mem = 0.f, s = 0.f;
    for (int cp = 0; cp < 5; ++cp) {
        const int c0 = 2 * cp;
        #pragma unroll
        for (int i = 0; i < CH; ++i)
            Bv[i] = cm[(size_t)((c0 + 1) * CH + i) * str + base];
        #pragma unroll
        for (int i = 0; i < CH; ++i) {
            const int t = c0 * CH + i;
            const float m = __fsub_rn(__fadd_rn(__fmul_rn(0.95f, mem), A[i]), s);
            mem = m; s = (m > 1.0f) ? 1.0f : 0.0f;
            os[(size_t)t * str + base] = s;
            cm[(size_t)t * str + base] = m;
        }
        if (cp < 4) {
            #pragma unroll
            for (int i = 0; i < CH; ++i)
                A[i] = cm[(size_t)((c0 + 2) * CH + i) * str + base];
        }
        #pragma unroll
        for (int i = 0; i < CH; ++i) {
            const int t = (c0 + 1) * CH + i;
            const float m = __fsub_rn(__fadd_rn(__fmul_rn(0.95f, mem), Bv[i]), s);
            mem = m; s = (m > 1.0f) ? 1.0f : 0.0f;
            os[(size_t)t * str + base] = s;
            cm[(size_t)t * str + base] = m;
        }
    }
}

extern "C" void kernel_launch(void* const* d_in, const int* in_sizes, int n_in,
                              void* d_out, int out_size, void* d_ws, size_t ws_size,
                              hipStream_t stream) {
    const float* x  = (const float*)d_in[0];
    const float* W1 = (const float*)d_in[1];
    const float* b1 = (const float*)d_in[2];
    const float* W2 = (const float*)d_in[3];
    const float* b2 = (const float*)d_in[4];
    float* outs = (float*)d_out;                                   // (T,B,80) spikes
    float* outm = outs + (size_t)T_STEPS * BATCH * N_OUT;          // (T,B,80) mem

    k1_cur1<<<BATCH * 25, 64, 0, stream>>>(x, W1, b1, outs);       // cur1 -> outs
    k2_rec1<<<BATCH, 64, 0, stream>>>(outs);                       // spk overwrites cur1
    k3_cur2<<<BATCH * 8, 64, 0, stream>>>(outs, W2, b2, outm);     // cur2 -> outm
    k4_rec2<<<BATCH, 80, 0, stream>>>(outm, outs);                 // finals in place
}

// Round 5
// 174.161 us; speedup vs baseline: 2.7726x; 2.7726x over previous
//
#include <hip/hip_runtime.h>

// SNN classifier: T=500, B=256, 96 -> 64 -> 80, leaky (subtract reset).
// f32 BLAS-order arithmetic replicated exactly (single-accumulator
// k-ascending __fmaf_rn chains; fixed leaky op-sequence) -> outputs
// bitwise-identical to the passing round-2/3/4 kernels.
//
// Round-5: round-4's K1 spilled w[96] to scratch (VGPR=84 < 96, FETCH
// 482MB of spill traffic, 420us). Arrays >~48 elems don't reliably promote.
// Fix: stream weights in 16-register chunks (#pragma unroll 1 on the chunk
// loop => chunks sequential, never co-live), accumulators carried across
// chunks. Per-(t,h) k-chain still single-acc ascending => bitwise-same.
//
//   K1: block=64 (lane=h), one b + 20 timesteps per block. acc[20] VGPR,
//       W1 chunk w[16] VGPR per-lane, x via wave-uniform s_loads. No LDS.
//   K2: unchanged (chunk-prefetched in-place recurrence).
//   K3: block=64 (lane=t), one b + 64-t tile. acc[40] per o-half, spk row
//       streamed in 4x16-reg chunks (L1-resident, read twice), W2 rows
//       wave-uniform s_loads. Direct per-lane float4 stores (no LDS).
//   K4: unchanged.

#define T_STEPS 500
#define BATCH   256
#define N_IN    96
#define N_HID   64
#define N_OUT   80
#define CH      50   // chunk size in K2/K4 (500 = 10*50)

// ---------------- K1: cur1 = x @ W1 + b1 ----------------
// grid 256*25, block 64. Each block: one b, 20 timesteps.
__global__ __launch_bounds__(64) void k1_cur1(
    const float* __restrict__ x,   // (T,B,96)
    const float* __restrict__ W1,  // (96,64)
    const float* __restrict__ b1,  // (64)
    float* __restrict__ cur1)      // (T,B,64) region inside outs
{
    const int b  = blockIdx.x / 25;
    const int tc = blockIdx.x % 25;
    const int h  = threadIdx.x;    // 0..63
    const int t0 = tc * 20;
    const float bb = b1[h];

    float acc[20];
    #pragma unroll
    for (int j = 0; j < 20; ++j) acc[j] = 0.0f;

    #pragma unroll 1                       // chunks strictly sequential
    for (int kc = 0; kc < 6; ++kc) {
        float w[16];                       // per-lane W1 chunk (16 VGPR)
        #pragma unroll
        for (int j = 0; j < 16; ++j)
            w[j] = W1[(size_t)(kc * 16 + j) * N_HID + h];

        #pragma unroll
        for (int tl = 0; tl < 20; ++tl) {
            const float4* __restrict__ xr = reinterpret_cast<const float4*>(
                x + ((size_t)(t0 + tl) * BATCH + b) * N_IN + kc * 16);
            #pragma unroll
            for (int q = 0; q < 4; ++q) {
                const float4 xv = xr[q];   // wave-uniform -> s_load_dwordx4
                acc[tl] = __fmaf_rn(xv.x, w[q * 4 + 0], acc[tl]);
                acc[tl] = __fmaf_rn(xv.y, w[q * 4 + 1], acc[tl]);
                acc[tl] = __fmaf_rn(xv.z, w[q * 4 + 2], acc[tl]);
                acc[tl] = __fmaf_rn(xv.w, w[q * 4 + 3], acc[tl]);
            }
        }
    }

    #pragma unroll
    for (int tl = 0; tl < 20; ++tl)
        cur1[((size_t)(t0 + tl) * BATCH + b) * N_HID + h] = __fadd_rn(acc[tl], bb);
}

// ---------------- K2: layer-1 recurrence (in-place cur1 -> spk) ----------------
__global__ __launch_bounds__(64) void k2_rec1(float* cs)  // outs region
{
    const int b = blockIdx.x;
    const int h = threadIdx.x;
    const size_t str  = (size_t)BATCH * N_HID;
    const size_t base = (size_t)b * N_HID + h;

    float A[CH], Bv[CH];
    #pragma unroll
    for (int i = 0; i < CH; ++i) A[i] = cs[(size_t)i * str + base];

    float mem = 0.f, s = 0.f;
    for (int cp = 0; cp < 5; ++cp) {            // 10 chunks, processed in pairs
        const int c0 = 2 * cp;
        #pragma unroll
        for (int i = 0; i < CH; ++i)            // prefetch chunk c0+1
            Bv[i] = cs[(size_t)((c0 + 1) * CH + i) * str + base];
        #pragma unroll
        for (int i = 0; i < CH; ++i) {          // compute chunk c0 from A
            const float m = __fsub_rn(__fadd_rn(__fmul_rn(0.95f, mem), A[i]), s);
            mem = m; s = (m > 1.0f) ? 1.0f : 0.0f;
            cs[(size_t)(c0 * CH + i) * str + base] = s;
        }
        if (cp < 4) {
            #pragma unroll
            for (int i = 0; i < CH; ++i)        // prefetch chunk c0+2
                A[i] = cs[(size_t)((c0 + 2) * CH + i) * str + base];
        }
        #pragma unroll
        for (int i = 0; i < CH; ++i) {          // compute chunk c0+1 from Bv
            const float m = __fsub_rn(__fadd_rn(__fmul_rn(0.95f, mem), Bv[i]), s);
            mem = m; s = (m > 1.0f) ? 1.0f : 0.0f;
            cs[(size_t)((c0 + 1) * CH + i) * str + base] = s;
        }
    }
}

// ---------------- K3: cur2 = spk @ W2 + b2 ----------------
// grid 256*8, block 64. Each block: one b, one 64-t tile (last tile 52).
__global__ __launch_bounds__(64) void k3_cur2(
    const float* __restrict__ spk,  // (T,B,64) in outs
    const float* __restrict__ W2,   // (64,80)
    const float* __restrict__ b2,   // (80)
    float* __restrict__ cur2)       // (T,B,80) = outm region
{
    const int b    = blockIdx.x >> 3;
    const int tc   = blockIdx.x & 7;
    const int lane = threadIdx.x;           // = t within tile
    const int t    = tc * 64 + lane;        // 0..511
    const int tt   = (t < T_STEPS) ? t : (T_STEPS - 1);  // clamp loads

    const float* __restrict__ sp = spk + ((size_t)tt * BATCH + b) * N_HID;

    #pragma unroll 1
    for (int half = 0; half < 2; ++half) {
        const int o0 = half * 40;
        float acc[40];
        #pragma unroll
        for (int o = 0; o < 40; ++o) acc[o] = 0.0f;

        #pragma unroll 1                   // spk chunks strictly sequential
        for (int hc = 0; hc < 4; ++hc) {
            float sr[16];                  // per-lane spk chunk (16 VGPR)
            const float4* __restrict__ sp4 =
                reinterpret_cast<const float4*>(sp + hc * 16);
            #pragma unroll
            for (int q = 0; q < 4; ++q) {
                const float4 v = sp4[q];   // per-lane, 64B line per lane (L1)
                sr[q * 4 + 0] = v.x; sr[q * 4 + 1] = v.y;
                sr[q * 4 + 2] = v.z; sr[q * 4 + 3] = v.w;
            }
            #pragma unroll
            for (int j = 0; j < 16; ++j) { // ascending-h single-acc chains
                const int hh = hc * 16 + j;
                const float4* __restrict__ wr =
                    reinterpret_cast<const float4*>(W2 + (size_t)hh * N_OUT + o0);
                const float sv = sr[j];
                #pragma unroll
                for (int o4 = 0; o4 < 10; ++o4) {
                    const float4 wv = wr[o4];  // wave-uniform -> s_load
                    acc[o4 * 4 + 0] = __fmaf_rn(sv, wv.x, acc[o4 * 4 + 0]);
                    acc[o4 * 4 + 1] = __fmaf_rn(sv, wv.y, acc[o4 * 4 + 1]);
                    acc[o4 * 4 + 2] = __fmaf_rn(sv, wv.z, acc[o4 * 4 + 2]);
                    acc[o4 * 4 + 3] = __fmaf_rn(sv, wv.w, acc[o4 * 4 + 3]);
                }
            }
        }

        if (t < T_STEPS) {
            float* dst = cur2 + ((size_t)t * BATCH + b) * N_OUT + o0;
            #pragma unroll
            for (int o4 = 0; o4 < 10; ++o4) {
                float4 v;
                v.x = __fadd_rn(acc[o4 * 4 + 0], b2[o0 + o4 * 4 + 0]);
                v.y = __fadd_rn(acc[o4 * 4 + 1], b2[o0 + o4 * 4 + 1]);
                v.z = __fadd_rn(acc[o4 * 4 + 2], b2[o0 + o4 * 4 + 2]);
                v.w = __fadd_rn(acc[o4 * 4 + 3], b2[o0 + o4 * 4 + 3]);
                reinterpret_cast<float4*>(dst)[o4] = v;
            }
        }
    }
}

// ---------------- K4: layer-2 recurrence (cur2 in outm -> spk/mem finals) ----------------
__global__ __launch_bounds__(80) void k4_rec2(float* cm, float* os)
{
    const int b = blockIdx.x;
    const int o = threadIdx.x;   // 0..79
    const size_t str  = (size_t)BATCH * N_OUT;
    const size_t base = (size_t)b * N_OUT + o;

    float A[CH], Bv[CH];
    #pragma unroll
    for (int i = 0; i < CH; ++i) A[i] = cm[(size_t)i * str + base];

    float mem = 0.f, s = 0.f;
    for (int cp = 0; cp < 5; ++cp) {
        const int c0 = 2 * cp;
        #pragma unroll
        for (int i = 0; i < CH; ++i)
            Bv[i] = cm[(size_t)((c0 + 1) * CH + i) * str + base];
        #pragma unroll
        for (int i = 0; i < CH; ++i) {
            const int t = c0 * CH + i;
            const float m = __fsub_rn(__fadd_rn(__fmul_rn(0.95f, mem), A[i]), s);
            mem = m; s = (m > 1.0f) ? 1.0f : 0.0f;
            os[(size_t)t * str + base] = s;
            cm[(size_t)t * str + base] = m;
        }
        if (cp < 4) {
            #pragma unroll
            for (int i = 0; i < CH; ++i)
                A[i] = cm[(size_t)((c0 + 2) * CH + i) * str + base];
        }
        #pragma unroll
        for (int i = 0; i < CH; ++i) {
            const int t = (c0 + 1) * CH + i;
            const float m = __fsub_rn(__fadd_rn(__fmul_rn(0.95f, mem), Bv[i]), s);
            mem = m; s = (m > 1.0f) ? 1.0f : 0.0f;
            os[(size_t)t * str + base] = s;
            cm[(size_t)t * str + base] = m;
        }
    }
}

extern "C" void kernel_launch(void* const* d_in, const int* in_sizes, int n_in,
                              void* d_out, int out_size, void* d_ws, size_t ws_size,
                              hipStream_t stream) {
    const float* x  = (const float*)d_in[0];
    const float* W1 = (const float*)d_in[1];
    const float* b1 = (const float*)d_in[2];
    const float* W2 = (const float*)d_in[3];
    const float* b2 = (const float*)d_in[4];
    float* outs = (float*)d_out;                                   // (T,B,80) spikes
    float* outm = outs + (size_t)T_STEPS * BATCH * N_OUT;          // (T,B,80) mem

    k1_cur1<<<BATCH * 25, 64, 0, stream>>>(x, W1, b1, outs);       // cur1 -> outs
    k2_rec1<<<BATCH, 64, 0, stream>>>(outs);                       // spk overwrites cur1
    k3_cur2<<<BATCH * 8, 64, 0, stream>>>(outs, W2, b2, outm);     // cur2 -> outm
    k4_rec2<<<BATCH, 80, 0, stream>>>(outm, outs);                 // finals in place
}